// Round 1
// baseline (200.903 us; speedup 1.0000x reference)
//
#include <hip/hip_runtime.h>

#define S_LEN 4096
#define NH 16
#define DH 64
#define NE 1024

typedef __bf16 bf16_t;
typedef __bf16 bf16x8 __attribute__((ext_vector_type(8)));
typedef __bf16 bf16x4 __attribute__((ext_vector_type(4)));
typedef __bf16 bf16x2 __attribute__((ext_vector_type(2)));
typedef float  f32x4  __attribute__((ext_vector_type(4)));

#define QSCALE 0.180336879f  // 0.125 * log2(e): softmax in exp2 domain

// ---------------------------------------------------------------------------
// Fused pack kernel (unchanged). Blocks [0,4096): q,k -> head-major bf16
// (q pre-scaled QSCALE) + W -> bf16, float4 vectorized. Blocks [4096,5120):
// V -> vt[h][d][t] transpose via LDS, bf16x2 (dword) writes.
// ---------------------------------------------------------------------------
__global__ __launch_bounds__(256) void pack_all(const float* __restrict__ q,
                                                const float* __restrict__ k,
                                                const float* __restrict__ w,
                                                const float* __restrict__ v,
                                                bf16_t* __restrict__ qb,
                                                bf16_t* __restrict__ kb,
                                                bf16_t* __restrict__ wb,
                                                bf16_t* __restrict__ vt) {
    __shared__ bf16_t tile[64][65];
    const int bid = blockIdx.x;
    if (bid < 4096) {
        const int tid = bid * 256 + threadIdx.x;
        const int e = tid * 4;
        const int s = e >> 10;
        const int c = e & (NE - 1);
        const int h = c >> 6;
        const int d = c & (DH - 1);
        const int o = (h * S_LEN + s) * DH + d;
        float4 qv = *(const float4*)(q + e);
        float4 kv = *(const float4*)(k + e);
        bf16x4 qo, ko;
        qo[0] = (bf16_t)(qv.x * QSCALE); qo[1] = (bf16_t)(qv.y * QSCALE);
        qo[2] = (bf16_t)(qv.z * QSCALE); qo[3] = (bf16_t)(qv.w * QSCALE);
        ko[0] = (bf16_t)kv.x; ko[1] = (bf16_t)kv.y; ko[2] = (bf16_t)kv.z; ko[3] = (bf16_t)kv.w;
        *(bf16x4*)(qb + o) = qo;
        *(bf16x4*)(kb + o) = ko;
        if (tid < (NE * NE / 4)) {
            float4 wv = *(const float4*)(w + tid * 4);
            bf16x4 wo;
            wo[0] = (bf16_t)wv.x; wo[1] = (bf16_t)wv.y; wo[2] = (bf16_t)wv.z; wo[3] = (bf16_t)wv.w;
            *(bf16x4*)(wb + tid * 4) = wo;
        }
    } else {
        const int vb = bid - 4096;
        const int h  = vb >> 6;
        const int t0 = (vb & 63) * 64;
        const int r  = threadIdx.x >> 6;   // 0..3
        const int cl = threadIdx.x & 63;
#pragma unroll
        for (int rep = 0; rep < 16; ++rep) {
            int i = rep * 4 + r;
            tile[cl][i] = (bf16_t)v[(t0 + i) * NE + h * DH + cl];
        }
        __syncthreads();
        const int r2  = threadIdx.x >> 5;        // 0..7
        const int cl2 = (threadIdx.x & 31) * 2;  // 0..62 even
#pragma unroll
        for (int rep = 0; rep < 8; ++rep) {
            int d = rep * 8 + r2;
            bf16x2 out;
            out[0] = tile[d][cl2];
            out[1] = tile[d][cl2 + 1];
            *(bf16x2*)(vt + (h * DH + d) * S_LEN + t0 + cl2) = out;
        }
    }
}

// ---------------------------------------------------------------------------
// Flash attention v8: 4 waves x 32 queries (was 8 x 16). K/V LDS fragment
// reads are shared across both 16-row groups of a wave -> per-block-tile LDS
// traffic 176KB -> 112KB. pbuf P-stores XOR-swizzled (col ^= 8*((row>>2)&7))
// to kill the 4-way ds_write_b16 bank conflicts; the b128 reload applies the
// same row-dependent XOR (multiples of 8 keep 16B-contiguous runs intact).
// Same fold/phase math, double-buffering, po/ls partial interface as v7.
// LDS total unchanged at 55296B -> still 2 blocks/CU.
// ---------------------------------------------------------------------------
__global__ __launch_bounds__(256, 2) void attn(const bf16_t* __restrict__ qb,
                                               const bf16_t* __restrict__ kb,
                                               const bf16_t* __restrict__ vt,
                                               float* __restrict__ po,
                                               float* __restrict__ ls) {
    __shared__ __align__(16) bf16_t kbuf[2][64 * 72];
    __shared__ __align__(16) bf16_t vbuf[2][64 * 72];
    __shared__ __align__(16) bf16_t pbuf[4][32 * 72];

    const int tid  = threadIdx.x;
    const int wave = tid >> 6;        // 0..3
    const int lane = tid & 63;
    const int l15  = lane & 15;
    const int quad = lane >> 4;
    const int h = blockIdx.x;
    const int x = blockIdx.y;

    const int sA = x;
    const int sB = 31 - x;
    const int n0 = x + 1;            // phase0 tile count
    const int b1 = sB + 1;           // phase1 first tile
    const int N  = 33;               // constant for all x

    const bf16_t* __restrict__ qh = qb + h * (S_LEN * DH);
    const bf16_t* __restrict__ kh = kb + h * (S_LEN * DH);
    const bf16_t* __restrict__ vh = vt + h * (DH * S_LEN);

    const int row0 = tid >> 3;        // 0..31 (second half adds 32)
    const int tc8  = (tid & 7) * 8;   // 0..56

    f32x4 o_acc[2][4];
    float lsum[2][4];
    bf16x8 qA[2][2];                  // [row-group][d-chunk]
    int s0 = sA * 128 + wave * 32;

    auto load_q = [&](int s0_) {
#pragma unroll
        for (int g = 0; g < 2; ++g)
#pragma unroll
            for (int dc = 0; dc < 2; ++dc)
                qA[g][dc] = *(const bf16x8*)(qh + (s0_ + g * 16 + l15) * DH + dc * 32 + quad * 8);
    };
    auto reset_acc = [&]() {
#pragma unroll
        for (int g = 0; g < 2; ++g) {
#pragma unroll
            for (int db = 0; db < 4; ++db) o_acc[g][db] = (f32x4){0.f, 0.f, 0.f, 0.f};
#pragma unroll
            for (int r = 0; r < 4; ++r) lsum[g][r] = 0.0f;
        }
    };
    auto epilogue = [&](int s0_, int slot) {
        float l2[2][4];
#pragma unroll
        for (int g = 0; g < 2; ++g)
#pragma unroll
            for (int r = 0; r < 4; ++r) l2[g][r] = lsum[g][r];
#pragma unroll
        for (int off = 8; off >= 1; off >>= 1)
#pragma unroll
            for (int g = 0; g < 2; ++g)
#pragma unroll
                for (int r = 0; r < 4; ++r) l2[g][r] += __shfl_xor(l2[g][r], off, 64);
        float* poz = po + (size_t)(slot * NH + h) * S_LEN * DH;
#pragma unroll
        for (int g = 0; g < 2; ++g)
#pragma unroll
            for (int db = 0; db < 4; ++db)
#pragma unroll
                for (int r = 0; r < 4; ++r)
                    poz[(s0_ + g * 16 + quad * 4 + r) * DH + db * 16 + l15] = o_acc[g][db][r];
        if (l15 == 0) {
            float* lsz = ls + (size_t)(slot * NH + h) * S_LEN;
#pragma unroll
            for (int g = 0; g < 2; ++g)
#pragma unroll
                for (int r = 0; r < 4; ++r) lsz[s0_ + g * 16 + quad * 4 + r] = l2[g][r];
        }
    };

    load_q(s0);
    reset_acc();

    {
        bf16x8 kr0 = *(const bf16x8*)(kh + row0 * DH + tc8);
        bf16x8 kr1 = *(const bf16x8*)(kh + (row0 + 32) * DH + tc8);
        bf16x8 vr0 = *(const bf16x8*)(vh + row0 * S_LEN + tc8);
        bf16x8 vr1 = *(const bf16x8*)(vh + (row0 + 32) * S_LEN + tc8);
        *(bf16x8*)(kbuf[0] + row0 * 72 + tc8) = kr0;
        *(bf16x8*)(kbuf[0] + (row0 + 32) * 72 + tc8) = kr1;
        *(bf16x8*)(vbuf[0] + row0 * 72 + tc8) = vr0;
        *(bf16x8*)(vbuf[0] + (row0 + 32) * 72 + tc8) = vr1;
    }
    __syncthreads();

    for (int j = 0; j < N; ++j) {
        if (j == n0) {  // phase switch (block-uniform)
            epilogue(s0, 0);
            s0 = sB * 128 + wave * 32;
            load_q(s0);
            reset_acc();
        }
        const int t0 = (j < n0 ? j : b1 + (j - n0)) * 64;
        const bf16_t* kb_ = kbuf[j & 1];
        const bf16_t* vb_ = vbuf[j & 1];

        bf16x8 kr0n, kr1n, vr0n, vr1n;
        const bool pf = (j + 1 < N);
        if (pf) {
            const int jn = j + 1;
            const int tn = (jn < n0 ? jn : b1 + (jn - n0)) * 64;
            kr0n = *(const bf16x8*)(kh + (tn + row0) * DH + tc8);
            kr1n = *(const bf16x8*)(kh + (tn + row0 + 32) * DH + tc8);
            vr0n = *(const bf16x8*)(vh + row0 * S_LEN + tn + tc8);
            vr1n = *(const bf16x8*)(vh + (row0 + 32) * S_LEN + tn + tc8);
        }

        // QK^T: K fragments read ONCE per wave, reused for both row-groups.
        f32x4 c_[2][4];
#pragma unroll
        for (int ch = 0; ch < 4; ++ch) {
            bf16x8 kB0 = *(const bf16x8*)(kb_ + (ch * 16 + l15) * 72 + quad * 8);
            bf16x8 kB1 = *(const bf16x8*)(kb_ + (ch * 16 + l15) * 72 + 32 + quad * 8);
#pragma unroll
            for (int g = 0; g < 2; ++g) {
                f32x4 zr = (f32x4){0.f, 0.f, 0.f, 0.f};
                zr = __builtin_amdgcn_mfma_f32_16x16x32_bf16(qA[g][0], kB0, zr, 0, 0, 0);
                zr = __builtin_amdgcn_mfma_f32_16x16x32_bf16(qA[g][1], kB1, zr, 0, 0, 0);
                c_[g][ch] = zr;
            }
        }

        if (t0 + 63 > s0) {
#pragma unroll
            for (int g = 0; g < 2; ++g)
#pragma unroll
                for (int ch = 0; ch < 4; ++ch) {
                    int col = t0 + ch * 16 + l15;
#pragma unroll
                    for (int r = 0; r < 4; ++r) {
                        int row = s0 + g * 16 + quad * 4 + r;
                        if (col > row) c_[g][ch][r] = -INFINITY;
                    }
                }
        }

        // P stores: XOR-swizzled by 8*((row>>2)&7) -> all 32 banks per store
        // instruction (was 4-way conflicted at plain stride-72).
        bf16_t* pl = pbuf[wave];
#pragma unroll
        for (int g = 0; g < 2; ++g) {
            const int pswz = ((g * 4 + quad) & 7) * 8;
#pragma unroll
            for (int ch = 0; ch < 4; ++ch)
#pragma unroll
                for (int r = 0; r < 4; ++r) {
                    float p = exp2f(c_[g][ch][r] - 17.0f);
                    lsum[g][r] += p;
                    pl[(g * 16 + quad * 4 + r) * 72 + ((ch * 16 + l15) ^ pswz)] = (bf16_t)p;
                }
        }

        __builtin_amdgcn_wave_barrier();

        // P reload as A-fragments: same per-row XOR (multiple of 8 keeps the
        // 8-element run contiguous, so b128 reads stay legal).
        bf16x8 pA[2][2];
#pragma unroll
        for (int g = 0; g < 2; ++g) {
            const int rswz = ((g * 4 + (l15 >> 2)) & 7) * 8;
#pragma unroll
            for (int kc = 0; kc < 2; ++kc)
                pA[g][kc] = *(const bf16x8*)(pl + (g * 16 + l15) * 72 + ((kc * 32 + quad * 8) ^ rswz));
        }

        // V fragments read ONCE per wave, reused for both row-groups.
        bf16x8 vB[4][2];
#pragma unroll
        for (int db = 0; db < 4; ++db)
#pragma unroll
            for (int kc = 0; kc < 2; ++kc)
                vB[db][kc] = *(const bf16x8*)(vb_ + (db * 16 + l15) * 72 + kc * 32 + quad * 8);

#pragma unroll
        for (int g = 0; g < 2; ++g)
#pragma unroll
            for (int db = 0; db < 4; ++db) {
                o_acc[g][db] = __builtin_amdgcn_mfma_f32_16x16x32_bf16(pA[g][0], vB[db][0], o_acc[g][db], 0, 0, 0);
                o_acc[g][db] = __builtin_amdgcn_mfma_f32_16x16x32_bf16(pA[g][1], vB[db][1], o_acc[g][db], 0, 0, 0);
            }

        if (pf) {
            bf16_t* kd = kbuf[(j + 1) & 1];
            bf16_t* vd = vbuf[(j + 1) & 1];
            *(bf16x8*)(kd + row0 * 72 + tc8) = kr0n;
            *(bf16x8*)(kd + (row0 + 32) * 72 + tc8) = kr1n;
            *(bf16x8*)(vd + row0 * 72 + tc8) = vr0n;
            *(bf16x8*)(vd + (row0 + 32) * 72 + tc8) = vr1n;
        }
        __syncthreads();
    }

    epilogue(s0, 1);
}

// ---------------------------------------------------------------------------
// Combine (unchanged): xb[row][h*64+d] = (o0 + o1) / (l0 + l1).
// ---------------------------------------------------------------------------
__global__ __launch_bounds__(256) void combine(const float* __restrict__ po,
                                               const float* __restrict__ ls,
                                               bf16_t* __restrict__ xb) {
    const int idx = blockIdx.x * 256 + threadIdx.x;
    const int row = idx >> 8;
    const int c   = (idx & 255) * 4;
    const int h   = c >> 6;
    const int d   = c & 63;
    const size_t base0 = (size_t)(h) * S_LEN * DH + row * DH + d;
    const size_t base1 = (size_t)(NH + h) * S_LEN * DH + row * DH + d;
    float4 o0 = *(const float4*)(po + base0);
    float4 o1 = *(const float4*)(po + base1);
    float l = ls[(size_t)h * S_LEN + row] + ls[(size_t)(NH + h) * S_LEN + row];
    float inv = 1.0f / l;
    bf16x4 out;
    out[0] = (bf16_t)((o0.x + o1.x) * inv);
    out[1] = (bf16_t)((o0.y + o1.y) * inv);
    out[2] = (bf16_t)((o0.z + o1.z) * inv);
    out[3] = (bf16_t)((o0.w + o1.w) * inv);
    *(bf16x4*)(xb + (size_t)row * NE + c) = out;
}

// ---------------------------------------------------------------------------
// Projection (unchanged): Y[4096][1024] = X(bf16) @ W^T(bf16), fp32 out.
// ---------------------------------------------------------------------------
__global__ __launch_bounds__(256, 4) void proj(const bf16_t* __restrict__ xb,
                                               const bf16_t* __restrict__ wb,
                                               float* __restrict__ y) {
    __shared__ __align__(16) bf16_t wbuf[2][64 * 72];
    const int tid  = threadIdx.x;
    const int wave = tid >> 6;
    const int lane = tid & 63;
    const int l15  = lane & 15;
    const int quad = lane >> 4;
    const int m0 = blockIdx.x * 64 + wave * 16;
    const int n0 = blockIdx.y * 64;

    const int row0 = tid >> 3;        // 0..31 (second chunk adds 32)
    const int tc8  = (tid & 7) * 8;

    f32x4 acc[4];
#pragma unroll
    for (int nb = 0; nb < 4; ++nb) acc[nb] = (f32x4){0.f, 0.f, 0.f, 0.f};

    {
        bf16x8 wr0 = *(const bf16x8*)(wb + (n0 + row0) * NE + tc8);
        bf16x8 wr1 = *(const bf16x8*)(wb + (n0 + row0 + 32) * NE + tc8);
        *(bf16x8*)(wbuf[0] + row0 * 72 + tc8) = wr0;
        *(bf16x8*)(wbuf[0] + (row0 + 32) * 72 + tc8) = wr1;
    }
    bf16x8 a[2];
#pragma unroll
    for (int kc = 0; kc < 2; ++kc)
        a[kc] = *(const bf16x8*)(xb + (m0 + l15) * NE + kc * 32 + quad * 8);
    __syncthreads();

    for (int kt = 0; kt < 16; ++kt) {
        const bf16_t* wb_ = wbuf[kt & 1];
        const bool pf = (kt + 1 < 16);
        bf16x8 wr0, wr1, an[2];
        if (pf) {
            const int kn = (kt + 1) * 64;
            wr0 = *(const bf16x8*)(wb + (n0 + row0) * NE + kn + tc8);
            wr1 = *(const bf16x8*)(wb + (n0 + row0 + 32) * NE + kn + tc8);
#pragma unroll
            for (int kc = 0; kc < 2; ++kc)
                an[kc] = *(const bf16x8*)(xb + (m0 + l15) * NE + kn + kc * 32 + quad * 8);
        }

#pragma unroll
        for (int nb = 0; nb < 4; ++nb)
#pragma unroll
            for (int kc = 0; kc < 2; ++kc) {
                bf16x8 b = *(const bf16x8*)(wb_ + (nb * 16 + l15) * 72 + kc * 32 + quad * 8);
                acc[nb] = __builtin_amdgcn_mfma_f32_16x16x32_bf16(a[kc], b, acc[nb], 0, 0, 0);
            }

        if (pf) {
            *(bf16x8*)(wbuf[(kt + 1) & 1] + row0 * 72 + tc8) = wr0;
            *(bf16x8*)(wbuf[(kt + 1) & 1] + (row0 + 32) * 72 + tc8) = wr1;
#pragma unroll
            for (int kc = 0; kc < 2; ++kc) a[kc] = an[kc];
        }
        __syncthreads();
    }

#pragma unroll
    for (int nb = 0; nb < 4; ++nb)
#pragma unroll
        for (int r = 0; r < 4; ++r)
            y[(m0 + quad * 4 + r) * NE + n0 + nb * 16 + l15] = acc[nb][r];
}

extern "C" void kernel_launch(void* const* d_in, const int* in_sizes, int n_in,
                              void* d_out, int out_size, void* d_ws, size_t ws_size,
                              hipStream_t stream) {
    const float* q = (const float*)d_in[0];
    const float* k = (const float*)d_in[1];
    const float* v = (const float*)d_in[2];
    const float* w = (const float*)d_in[3];
    float* y = (float*)d_out;

    // ws: bf16 {qb 4M | kb 4M | vt 4M | wb 1M | xb 4M} then fp32 {po 8M | ls 128K}
    bf16_t* ws = (bf16_t*)d_ws;
    bf16_t* qb = ws;
    bf16_t* kb = qb + 4 * 1024 * 1024;
    bf16_t* vt = kb + 4 * 1024 * 1024;
    bf16_t* wb = vt + 4 * 1024 * 1024;
    bf16_t* xb = wb + 1024 * 1024;
    float*  po = (float*)(xb + 4 * 1024 * 1024);
    float*  ls = po + (size_t)2 * NH * S_LEN * DH;

    pack_all<<<dim3(4096 + 1024), dim3(256), 0, stream>>>(q, k, w, v, qb, kb, wb, vt);
    attn<<<dim3(NH, 32), dim3(256), 0, stream>>>(qb, kb, vt, po, ls);
    combine<<<dim3(4096), dim3(256), 0, stream>>>(po, ls, xb);
    proj<<<dim3(S_LEN / 64, NE / 64), dim3(256), 0, stream>>>(xb, wb, y);
}